// Round 1
// baseline (3207.231 us; speedup 1.0000x reference)
//
#include <hip/hip_runtime.h>
#include <math.h>

#define Bb 8
#define Nn 1024
#define Kk 32
#define Dd 256
#define Hh 8
#define DHh 32
#define TDIMt 16
#define NBnb 32
#define HIDh 128
#define Ll 4
#define NSns 128
#define SHDs 9
#define EINe 304   // NB + TDIM + 2*NS

__device__ __forceinline__ float gelu_tanh(float x){
  float x3 = x*x*x;
  return 0.5f*x*(1.0f + tanhf(0.7978845608028654f*(x + 0.044715f*x3)));
}

// ---------------- kNN: one wave (64 lanes) per (b,n) ----------------
__global__ __launch_bounds__(64) void knn_kernel(const float* __restrict__ x, int* __restrict__ src){
  int bn = blockIdx.x;
  int b = bn >> 10;
  int n = bn & (Nn-1);
  int lane = threadIdx.x;
  const float* xb = x + (size_t)b*Nn*3;
  float px = xb[n*3+0], py = xb[n*3+1], pz = xb[n*3+2];
  float d2v[16];
  #pragma unroll
  for (int i=0;i<16;i++){
    int j = i*64 + lane;
    float dx = px - xb[j*3+0];
    float dy = py - xb[j*3+1];
    float dz = pz - xb[j*3+2];
    d2v[i] = dx*dx + dy*dy + dz*dz;
  }
  for (int s=0;s<Kk;s++){
    float best = 3.0e38f; int bslot = 0;
    #pragma unroll
    for (int i=0;i<16;i++){
      if (d2v[i] < best){ best = d2v[i]; bslot = i; }
    }
    int bj = bslot*64 + lane;
    #pragma unroll
    for (int off=32; off>=1; off>>=1){
      float ov = __shfl_xor(best, off);
      int   oj = __shfl_xor(bj,   off);
      if (ov < best || (ov == best && oj < bj)){ best = ov; bj = oj; }
    }
    if ((bj & 63) == lane){
      int sl = bj >> 6;
      #pragma unroll
      for (int i=0;i<16;i++) if (i==sl) d2v[i] = 3.0e38f;
    }
    if (lane == 0) src[(size_t)bn*Kk + s] = bj;
  }
}

// ---------------- embed: node = [y,t] @ W_embed ----------------
__global__ __launch_bounds__(256) void embed_kernel(const float* __restrict__ y, const float* __restrict__ t,
    const float* __restrict__ We, float* __restrict__ node){
  int bn = blockIdx.x; int b = bn >> 10;
  int c = threadIdx.x;
  float f0 = y[(size_t)bn*3+0], f1 = y[(size_t)bn*3+1], f2 = y[(size_t)bn*3+2];
  float a = f0*We[0*Dd+c] + f1*We[1*Dd+c] + f2*We[2*Dd+c];
  #pragma unroll
  for (int i=0;i<TDIMt;i++) a += t[b*TDIMt+i]*We[(3+i)*Dd+c];
  node[(size_t)bn*Dd + c] = a;
}

// ---------------- one transformer layer: block per (b,n) ----------------
__global__ __launch_bounds__(256) void layer_kernel(
    const float* __restrict__ x, const float* __restrict__ t, const int* __restrict__ src,
    const float* __restrict__ node_in, float* __restrict__ node_out, float* __restrict__ out3,
    const float* __restrict__ Wk1g, const float* __restrict__ bk1g, const float* __restrict__ Wk2g,
    const float* __restrict__ Wqg, const float* __restrict__ Wvg, const float* __restrict__ Wog,
    const float* __restrict__ Wo_out, int layer, int is_last){

  __shared__ float s_node[Dd];
  __shared__ float s_q[Dd];
  __shared__ float s_hsh[HIDh];
  __shared__ float s_vsrc[Kk][266];   // 256 node-src + 9 sh (+1 pad)
  __shared__ float s_rbf[Kk][NBnb];
  __shared__ float s_t[TDIMt];
  __shared__ float s_cut[Kk];
  __shared__ int   s_src[Kk];
  __shared__ float s_h[Kk][HIDh];     // later reused as pooled[8][266]
  __shared__ float s_qw[HIDh][Hh];
  __shared__ float s_logits[Kk][Hh];  // later alpha in place
  __shared__ float s_agg[Dd];

  const int tid = threadIdx.x;
  const int bn  = blockIdx.x;
  const int b   = bn >> 10;

  const float* wk1 = Wk1g + (size_t)layer*EINe*HIDh;
  const float* bk  = bk1g + layer*HIDh;
  const float* wk2 = Wk2g + (size_t)layer*HIDh*Dd;
  const float* wq  = Wqg  + (size_t)layer*Dd*Dd;
  const float* wv  = Wvg  + (size_t)layer*(Dd+SHDs)*Dd;

  // phase 1: loads
  s_node[tid] = node_in[(size_t)bn*Dd + tid];
  if (tid < TDIMt) s_t[tid] = t[b*TDIMt + tid];
  if (tid < Kk)    s_src[tid] = src[(size_t)bn*Kk + tid];
  __syncthreads();

  // phase 2: gather source features + geometry + q
  for (int k=0;k<Kk;k++){
    int j = s_src[k];
    s_vsrc[k][tid] = node_in[((size_t)b*Nn + j)*Dd + tid];
  }
  if (tid < Kk){
    int j = s_src[tid];
    float ax = x[(size_t)bn*3+0], ay = x[(size_t)bn*3+1], az = x[(size_t)bn*3+2];
    const float* xj = x + ((size_t)b*Nn + j)*3;
    float dx = ax - xj[0], dy = ay - xj[1], dz = az - xj[2];
    float r  = sqrtf(dx*dx + dy*dy + dz*dz);
    float inv = 1.0f / fmaxf(r, 1e-9f);
    float ux = dx*inv, uy = dy*inv, uz = dz*inv;
    s_vsrc[tid][Dd+0] = 1.0f;
    s_vsrc[tid][Dd+1] = 1.7320508075688772f*ux;
    s_vsrc[tid][Dd+2] = 1.7320508075688772f*uy;
    s_vsrc[tid][Dd+3] = 1.7320508075688772f*uz;
    s_vsrc[tid][Dd+4] = 3.872983346207417f*ux*uy;
    s_vsrc[tid][Dd+5] = 3.872983346207417f*uy*uz;
    s_vsrc[tid][Dd+6] = 1.118033988749895f*(3.0f*uz*uz - 1.0f);
    s_vsrc[tid][Dd+7] = 3.872983346207417f*ux*uz;
    s_vsrc[tid][Dd+8] = 1.9364916731037085f*(ux*ux - uy*uy);
    float xx = 10.0f*(1.0f - r*0.5f);
    float cu = (xx > 0.0f) ? 1.4f*expf(-1.0f/xx) : 0.0f;
    s_cut[tid] = cu;
    const float stp = 2.0f/31.0f;
    for (int i=0;i<NBnb;i++){
      float dd = (r - stp*(float)i)*(31.0f/2.0f);
      s_rbf[tid][i] = expf(-dd*dd)*(1.0f/1.12f)*5.374011537017762f*cu;
    }
  }
  {
    float a = 0.0f;
    for (int i=0;i<Dd;i++) a += s_node[i]*wq[i*Dd + tid];
    s_q[tid] = a;
  }
  __syncthreads();

  // phase 3: qW[c][hh] = sum_d q[hh*32+d]*Wk2[c][hh*32+d]; shared part of h
  for (int rep=0; rep<4; rep++){
    int idx = tid + rep*256;
    int c  = idx & (HIDh-1);
    int hh = idx >> 7;
    const float* w  = wk2 + c*Dd + hh*DHh;
    const float* qq = s_q + hh*DHh;
    float a = 0.0f;
    #pragma unroll
    for (int d=0; d<DHh; d++) a += qq[d]*w[d];
    s_qw[c][hh] = a;
  }
  if (tid < HIDh){
    float a = bk[tid];
    for (int i=0;i<TDIMt;i++) a += s_t[i]*wk1[(NBnb+i)*HIDh + tid];
    for (int i=0;i<NSns;i++)  a += s_node[i]*wk1[(NBnb+TDIMt+NSns+i)*HIDh + tid];
    s_hsh[tid] = a;
  }
  __syncthreads();

  // phase 4: per-edge h = gelu(e @ Wk1 + b). thread = (j, half); 16 edges per thread.
  {
    int jj = tid & (HIDh-1);
    int half = tid >> 7;
    float acc[16];
    #pragma unroll
    for (int kk=0;kk<16;kk++) acc[kk] = s_hsh[jj];
    for (int ce=0; ce<NBnb; ce++){
      float w = wk1[ce*HIDh + jj];
      #pragma unroll
      for (int kk=0;kk<16;kk++) acc[kk] += s_rbf[half*16+kk][ce]*w;
    }
    for (int ci=0; ci<NSns; ci++){
      float w = wk1[(NBnb+TDIMt+ci)*HIDh + jj];
      #pragma unroll
      for (int kk=0;kk<16;kk++) acc[kk] += s_vsrc[half*16+kk][ci]*w;
    }
    #pragma unroll
    for (int kk=0;kk<16;kk++) s_h[half*16+kk][jj] = gelu_tanh(acc[kk]);
  }
  __syncthreads();

  // phase 5: logits[k][hh] = (h[k] . qW[:,hh]) / sqrt(DH)
  {
    int k = tid >> 3, hh = tid & (Hh-1);
    float a = 0.0f;
    for (int c=0;c<HIDh;c++) a += s_h[k][c]*s_qw[c][hh];
    s_logits[k][hh] = a*0.17677669529663687f;
  }
  __syncthreads();

  // phase 6: cutoff-weighted softmax over k (per head)
  if (tid < Hh){
    float m = -3.0e38f;
    for (int k=0;k<Kk;k++) m = fmaxf(m, s_logits[k][tid]);
    float ssum = 0.0f;
    for (int k=0;k<Kk;k++){
      float w = s_cut[k]*expf(s_logits[k][tid] - m);
      s_logits[k][tid] = w;
      ssum += w;
    }
    float inv = 1.0f/(ssum + 1e-9f);
    for (int k=0;k<Kk;k++) s_logits[k][tid] *= inv;
  }
  __syncthreads();

  // phase 7: pooled[hh][c] = sum_k alpha[k][hh] * vsrc[k][c]   (reuse s_h storage)
  float* s_pool = &s_h[0][0];
  for (int idx=tid; idx < Hh*(Dd+SHDs); idx += 256){
    int hh = idx / (Dd+SHDs);
    int c  = idx - hh*(Dd+SHDs);
    float a = 0.0f;
    for (int k=0;k<Kk;k++) a += s_logits[k][hh]*s_vsrc[k][c];
    s_pool[hh*266 + c] = a;
  }
  __syncthreads();

  // phase 8: agg[j] = sum_c pooled[hh(j)][c] * Wv[c][j]
  {
    int hh = tid >> 5;
    const float* pp = s_pool + hh*266;
    float a = 0.0f;
    for (int c=0;c<Dd+SHDs;c++) a += pp[c]*wv[c*Dd + tid];
    s_agg[tid] = a;
  }
  __syncthreads();

  // phase 9: output projection
  if (!is_last){
    const float* wo = Wog + (size_t)layer*Dd*Dd;
    float a = s_node[tid];
    for (int i=0;i<Dd;i++) a += s_agg[i]*wo[i*Dd + tid];
    if (tid < 64)        a = gelu_tanh(a);
    else if (tid < NSns) a = tanhf(a);
    node_out[(size_t)bn*Dd + tid] = a;
  } else {
    if (tid < 3){
      float a = 0.0f;
      for (int i=0;i<Dd;i++) a += s_agg[i]*Wo_out[i*3 + tid];
      out3[(size_t)bn*3 + tid] = a;
    }
  }
}

extern "C" void kernel_launch(void* const* d_in, const int* in_sizes, int n_in,
                              void* d_out, int out_size, void* d_ws, size_t ws_size,
                              hipStream_t stream){
  const float* x   = (const float*)d_in[0];
  const float* y   = (const float*)d_in[1];
  const float* t   = (const float*)d_in[2];
  const float* We  = (const float*)d_in[3];
  const float* Wk1 = (const float*)d_in[4];
  const float* bk1 = (const float*)d_in[5];
  const float* Wk2 = (const float*)d_in[6];
  const float* Wq  = (const float*)d_in[7];
  const float* Wv  = (const float*)d_in[8];
  const float* Wo  = (const float*)d_in[9];
  const float* Woo = (const float*)d_in[10];
  float* out = (float*)d_out;

  char* ws = (char*)d_ws;
  int* src = (int*)ws;
  size_t off = (((size_t)Bb*Nn*Kk*sizeof(int)) + 255) & ~(size_t)255;
  float* nodeA = (float*)(ws + off);
  float* nodeB = nodeA + (size_t)Bb*Nn*Dd;

  dim3 grid(Bb*Nn);
  knn_kernel<<<grid, 64, 0, stream>>>(x, src);
  embed_kernel<<<grid, 256, 0, stream>>>(y, t, We, nodeA);
  layer_kernel<<<grid, 256, 0, stream>>>(x, t, src, nodeA, nodeB, nullptr, Wk1, bk1, Wk2, Wq, Wv, Wo, Woo, 0, 0);
  layer_kernel<<<grid, 256, 0, stream>>>(x, t, src, nodeB, nodeA, nullptr, Wk1, bk1, Wk2, Wq, Wv, Wo, Woo, 1, 0);
  layer_kernel<<<grid, 256, 0, stream>>>(x, t, src, nodeA, nodeB, nullptr, Wk1, bk1, Wk2, Wq, Wv, Wo, Woo, 2, 0);
  layer_kernel<<<grid, 256, 0, stream>>>(x, t, src, nodeB, nullptr, out,   Wk1, bk1, Wk2, Wq, Wv, Wo, Woo, 3, 1);
}

// Round 2
// 2006.400 us; speedup vs baseline: 1.5985x; 1.5985x over previous
//
#include <hip/hip_runtime.h>
#include <math.h>

#define Bb 8
#define Nn 1024
#define Kk 32
#define Dd 256
#define Hh 8
#define DHh 32
#define TDIMt 16
#define NBnb 32
#define HIDh 128
#define NSns 128
#define SHDs 9
#define EINe 304   // NB + TDIM + 2*NS

__device__ __forceinline__ float gelu_tanh(float x){
  float x3 = x*x*x;
  return 0.5f*x*(1.0f + tanhf(0.7978845608028654f*(x + 0.044715f*x3)));
}
__device__ __forceinline__ void fma4(float4& a, float s, const float4 w){
  a.x += s*w.x; a.y += s*w.y; a.z += s*w.z; a.w += s*w.w;
}
__device__ __forceinline__ float dot4(const float4 a, const float4 b){
  return a.x*b.x + a.y*b.y + a.z*b.z + a.w*b.w;
}

// ---------------- kNN: one wave per (b,n) ----------------
__global__ __launch_bounds__(64) void knn_kernel(const float* __restrict__ x, int* __restrict__ src){
  int bn = blockIdx.x;
  int b = bn >> 10;
  int n = bn & (Nn-1);
  int lane = threadIdx.x;
  const float* xb = x + (size_t)b*Nn*3;
  float px = xb[n*3+0], py = xb[n*3+1], pz = xb[n*3+2];
  float d2v[16];
  #pragma unroll
  for (int i=0;i<16;i++){
    int j = i*64 + lane;
    float dx = px - xb[j*3+0];
    float dy = py - xb[j*3+1];
    float dz = pz - xb[j*3+2];
    d2v[i] = dx*dx + dy*dy + dz*dz;
  }
  for (int s=0;s<Kk;s++){
    float best = 3.0e38f; int bslot = 0;
    #pragma unroll
    for (int i=0;i<16;i++){
      if (d2v[i] < best){ best = d2v[i]; bslot = i; }
    }
    int bj = bslot*64 + lane;
    #pragma unroll
    for (int off=32; off>=1; off>>=1){
      float ov = __shfl_xor(best, off);
      int   oj = __shfl_xor(bj,   off);
      if (ov < best || (ov == best && oj < bj)){ best = ov; bj = oj; }
    }
    if ((bj & 63) == lane){
      int sl = bj >> 6;
      #pragma unroll
      for (int i=0;i<16;i++) if (i==sl) d2v[i] = 3.0e38f;
    }
    if (lane == 0) src[(size_t)bn*Kk + s] = bj;
  }
}

// ---------------- embed ----------------
__global__ __launch_bounds__(256) void embed_kernel(const float* __restrict__ y, const float* __restrict__ t,
    const float* __restrict__ We, float* __restrict__ node){
  int bn = blockIdx.x; int b = bn >> 10;
  int c = threadIdx.x;
  float f0 = y[(size_t)bn*3+0], f1 = y[(size_t)bn*3+1], f2 = y[(size_t)bn*3+2];
  float a = f0*We[0*Dd+c] + f1*We[1*Dd+c] + f2*We[2*Dd+c];
  #pragma unroll
  for (int i=0;i<TDIMt;i++) a += t[b*TDIMt+i]*We[(3+i)*Dd+c];
  node[(size_t)bn*Dd + c] = a;
}

// ---------------- proj: per-node linear projections (tiled GEMM) ----------------
// grid (256 node-tiles, 6): y=0,1 -> q cols y*128; y=2 -> hsrc; y=3 -> hdst(+t+bias); y=4,5 -> vproj
__global__ __launch_bounds__(256) void proj_kernel(
    const float* __restrict__ node, const float* __restrict__ t,
    const float* __restrict__ Wqg, const float* __restrict__ Wk1g,
    const float* __restrict__ bk1g, const float* __restrict__ Wvg,
    float* __restrict__ q_all, float* __restrict__ hsrc_all,
    float* __restrict__ hdst_all, float* __restrict__ vproj_all, int layer){

  __shared__ float s_n[32][264];
  const int tid = threadIdx.x;
  const int n0  = blockIdx.x*32;
  const int y   = blockIdx.y;
  const int b   = n0 >> 10;

  { int m = tid>>6; int i4 = (tid&63)*4;
    #pragma unroll
    for (int r=0;r<8;r++){
      int mm = m + r*4;
      *(float4*)&s_n[mm][i4] = *(const float4*)&node[(size_t)(n0+mm)*Dd + i4];
    } }
  __syncthreads();

  const float* wk1l = Wk1g + (size_t)layer*EINe*HIDh;
  const float* W; int wstride, rows, outw, cb; float* outp;
  if (y < 2){        W = Wqg + (size_t)layer*Dd*Dd; wstride=Dd; rows=Dd; outp=q_all; outw=Dd; cb=y*128; }
  else if (y == 2){  W = wk1l + 48*HIDh;  wstride=HIDh; rows=128; outp=hsrc_all; outw=HIDh; cb=0; }
  else if (y == 3){  W = wk1l + 176*HIDh; wstride=HIDh; rows=128; outp=hdst_all; outw=HIDh; cb=0; }
  else {             W = Wvg + (size_t)layer*265*Dd; wstride=Dd; rows=Dd; outp=vproj_all; outw=Dd; cb=(y-4)*128; }

  const int m0 = (tid>>5)*4;
  const int c0 = cb + (tid&31)*4;
  float4 acc[4];
  #pragma unroll
  for (int mm=0;mm<4;mm++) acc[mm] = make_float4(0.f,0.f,0.f,0.f);

  for (int i=0;i<rows;i+=4){
    float4 a0 = *(const float4*)&s_n[m0+0][i];
    float4 a1 = *(const float4*)&s_n[m0+1][i];
    float4 a2 = *(const float4*)&s_n[m0+2][i];
    float4 a3 = *(const float4*)&s_n[m0+3][i];
    float4 w0 = *(const float4*)&W[(size_t)(i+0)*wstride + c0];
    float4 w1 = *(const float4*)&W[(size_t)(i+1)*wstride + c0];
    float4 w2 = *(const float4*)&W[(size_t)(i+2)*wstride + c0];
    float4 w3 = *(const float4*)&W[(size_t)(i+3)*wstride + c0];
    fma4(acc[0],a0.x,w0); fma4(acc[0],a0.y,w1); fma4(acc[0],a0.z,w2); fma4(acc[0],a0.w,w3);
    fma4(acc[1],a1.x,w0); fma4(acc[1],a1.y,w1); fma4(acc[1],a1.z,w2); fma4(acc[1],a1.w,w3);
    fma4(acc[2],a2.x,w0); fma4(acc[2],a2.y,w1); fma4(acc[2],a2.z,w2); fma4(acc[2],a2.w,w3);
    fma4(acc[3],a3.x,w0); fma4(acc[3],a3.y,w1); fma4(acc[3],a3.z,w2); fma4(acc[3],a3.w,w3);
  }

  if (y == 3){
    const float* bk = bk1g + layer*HIDh;
    const float* wt = wk1l + 32*HIDh;
    float4 tb = *(const float4*)&bk[c0];
    #pragma unroll
    for (int ii=0;ii<TDIMt;ii++){
      float tv = t[b*TDIMt + ii];
      fma4(tb, tv, *(const float4*)&wt[ii*HIDh + c0]);
    }
    #pragma unroll
    for (int mm=0;mm<4;mm++){ acc[mm].x+=tb.x; acc[mm].y+=tb.y; acc[mm].z+=tb.z; acc[mm].w+=tb.w; }
  }

  #pragma unroll
  for (int mm=0;mm<4;mm++)
    *(float4*)&outp[(size_t)(n0+m0+mm)*outw + c0] = acc[mm];
}

// ---------------- qw: qw[n][h][c] = sum_d q[n][h*32+d] * Wk2[c][h*32+d] ----------------
// grid (256 node-tiles, 8 heads)
__global__ __launch_bounds__(256) void qw_kernel(
    const float* __restrict__ q_all, const float* __restrict__ Wk2g,
    float* __restrict__ qw_all, int layer){
  __shared__ float s_q[32][36];
  const int tid = threadIdx.x;
  const int n0  = blockIdx.x*32;
  const int h   = blockIdx.y;
  const float* wk2l = Wk2g + (size_t)layer*HIDh*Dd;
  #pragma unroll
  for (int r=0;r<4;r++){
    int idx = tid + r*256;
    int m = idx>>5, d = idx&31;
    s_q[m][d] = q_all[(size_t)(n0+m)*Dd + h*DHh + d];
  }
  __syncthreads();
  const int m0 = (tid>>5)*4;
  const int c0 = (tid&31)*4;
  float4 acc[4];
  #pragma unroll
  for (int mm=0;mm<4;mm++) acc[mm] = make_float4(0.f,0.f,0.f,0.f);
  #pragma unroll
  for (int d=0; d<DHh; d+=4){
    float4 a0 = *(const float4*)&s_q[m0+0][d];
    float4 a1 = *(const float4*)&s_q[m0+1][d];
    float4 a2 = *(const float4*)&s_q[m0+2][d];
    float4 a3 = *(const float4*)&s_q[m0+3][d];
    float4 w0 = *(const float4*)&wk2l[(size_t)(c0+0)*Dd + h*DHh + d];
    float4 w1 = *(const float4*)&wk2l[(size_t)(c0+1)*Dd + h*DHh + d];
    float4 w2 = *(const float4*)&wk2l[(size_t)(c0+2)*Dd + h*DHh + d];
    float4 w3 = *(const float4*)&wk2l[(size_t)(c0+3)*Dd + h*DHh + d];
    acc[0].x += dot4(a0,w0); acc[0].y += dot4(a0,w1); acc[0].z += dot4(a0,w2); acc[0].w += dot4(a0,w3);
    acc[1].x += dot4(a1,w0); acc[1].y += dot4(a1,w1); acc[1].z += dot4(a1,w2); acc[1].w += dot4(a1,w3);
    acc[2].x += dot4(a2,w0); acc[2].y += dot4(a2,w1); acc[2].z += dot4(a2,w2); acc[2].w += dot4(a2,w3);
    acc[3].x += dot4(a3,w0); acc[3].y += dot4(a3,w1); acc[3].z += dot4(a3,w2); acc[3].w += dot4(a3,w3);
  }
  #pragma unroll
  for (int mm=0;mm<4;mm++)
    *(float4*)&qw_all[(size_t)(n0+m0+mm)*(HIDh*Hh) + h*HIDh + c0] = acc[mm];
}

// ---------------- attn: block per node ----------------
__global__ __launch_bounds__(256) void attn_kernel(
    const float* __restrict__ x, const int* __restrict__ src,
    const float* __restrict__ hsrc_all, const float* __restrict__ hdst_all,
    const float* __restrict__ vproj_all, const float* __restrict__ qw_all,
    const float* __restrict__ Wk1g, const float* __restrict__ Wvg,
    float* __restrict__ agg_all, int layer){

  __shared__ float s_rbf[Kk][36];
  __shared__ float s_sh[Kk][9];
  __shared__ float s_cut[Kk];
  __shared__ int   s_srcv[Kk];
  __shared__ float s_qw[Hh][132];
  __shared__ float s_h[Kk][132];
  __shared__ float s_alpha[Kk][9];
  __shared__ float s_poolsh[Hh][12];

  const int tid = threadIdx.x;
  const int bn  = blockIdx.x;
  const int b   = bn >> 10;
  const float* wk1rbf = Wk1g + (size_t)layer*EINe*HIDh;  // rows 0..31

  #pragma unroll
  for (int r=0;r<4;r++){
    int idx = tid + r*256;
    s_qw[idx>>7][idx&127] = qw_all[(size_t)bn*(HIDh*Hh) + idx];
  }
  if (tid < Kk){
    int j = src[(size_t)bn*Kk + tid]; s_srcv[tid] = j;
    float ax = x[(size_t)bn*3+0], ay = x[(size_t)bn*3+1], az = x[(size_t)bn*3+2];
    const float* xj = x + ((size_t)b*Nn + j)*3;
    float dx = ax - xj[0], dy = ay - xj[1], dz = az - xj[2];
    float rr = sqrtf(dx*dx + dy*dy + dz*dz);
    float inv = 1.0f / fmaxf(rr, 1e-9f);
    float ux = dx*inv, uy = dy*inv, uz = dz*inv;
    s_sh[tid][0] = 1.0f;
    s_sh[tid][1] = 1.7320508075688772f*ux;
    s_sh[tid][2] = 1.7320508075688772f*uy;
    s_sh[tid][3] = 1.7320508075688772f*uz;
    s_sh[tid][4] = 3.872983346207417f*ux*uy;
    s_sh[tid][5] = 3.872983346207417f*uy*uz;
    s_sh[tid][6] = 1.118033988749895f*(3.0f*uz*uz - 1.0f);
    s_sh[tid][7] = 3.872983346207417f*ux*uz;
    s_sh[tid][8] = 1.9364916731037085f*(ux*ux - uy*uy);
    float xx = 10.0f*(1.0f - rr*0.5f);
    float cu = (xx > 0.0f) ? 1.4f*expf(-1.0f/xx) : 0.0f;
    s_cut[tid] = cu;
    for (int i=0;i<NBnb;i++){
      float dd = (rr - (2.0f/31.0f)*(float)i)*(31.0f/2.0f);
      s_rbf[tid][i] = expf(-dd*dd)*(1.0f/1.12f)*5.374011537017762f*cu;
    }
  }
  __syncthreads();

  // per-edge h = gelu(rbf@Wk1_rbf + hdst[n] + hsrc[src]) : register-blocked GEMM
  {
    const int e0 = (tid>>5)*4;
    const int c0 = (tid&31)*4;
    float4 acc[4];
    #pragma unroll
    for (int mm=0;mm<4;mm++) acc[mm] = make_float4(0.f,0.f,0.f,0.f);
    #pragma unroll
    for (int ce=0; ce<NBnb; ce+=4){
      float4 a0 = *(const float4*)&s_rbf[e0+0][ce];
      float4 a1 = *(const float4*)&s_rbf[e0+1][ce];
      float4 a2 = *(const float4*)&s_rbf[e0+2][ce];
      float4 a3 = *(const float4*)&s_rbf[e0+3][ce];
      float4 w0 = *(const float4*)&wk1rbf[(ce+0)*HIDh + c0];
      float4 w1 = *(const float4*)&wk1rbf[(ce+1)*HIDh + c0];
      float4 w2 = *(const float4*)&wk1rbf[(ce+2)*HIDh + c0];
      float4 w3 = *(const float4*)&wk1rbf[(ce+3)*HIDh + c0];
      fma4(acc[0],a0.x,w0); fma4(acc[0],a0.y,w1); fma4(acc[0],a0.z,w2); fma4(acc[0],a0.w,w3);
      fma4(acc[1],a1.x,w0); fma4(acc[1],a1.y,w1); fma4(acc[1],a1.z,w2); fma4(acc[1],a1.w,w3);
      fma4(acc[2],a2.x,w0); fma4(acc[2],a2.y,w1); fma4(acc[2],a2.z,w2); fma4(acc[2],a2.w,w3);
      fma4(acc[3],a3.x,w0); fma4(acc[3],a3.y,w1); fma4(acc[3],a3.z,w2); fma4(acc[3],a3.w,w3);
    }
    float4 hd = *(const float4*)&hdst_all[(size_t)bn*HIDh + c0];
    #pragma unroll
    for (int mm=0;mm<4;mm++){
      int j = s_srcv[e0+mm];
      float4 hs = *(const float4*)&hsrc_all[((size_t)b*Nn + j)*HIDh + c0];
      float4 v;
      v.x = gelu_tanh(acc[mm].x + hd.x + hs.x);
      v.y = gelu_tanh(acc[mm].y + hd.y + hs.y);
      v.z = gelu_tanh(acc[mm].z + hd.z + hs.z);
      v.w = gelu_tanh(acc[mm].w + hd.w + hs.w);
      *(float4*)&s_h[e0+mm][c0] = v;
    }
  }
  __syncthreads();

  // logits
  {
    const int k = tid>>3, hh = tid&7;
    float a = 0.0f;
    #pragma unroll
    for (int c=0;c<HIDh;c+=4)
      a += dot4(*(const float4*)&s_h[k][c], *(const float4*)&s_qw[hh][c]);
    s_alpha[k][hh] = a*0.17677669529663687f;
  }
  __syncthreads();

  if (tid < Hh){
    float m = -3.0e38f;
    for (int k=0;k<Kk;k++) m = fmaxf(m, s_alpha[k][tid]);
    float ss = 0.0f;
    for (int k=0;k<Kk;k++){
      float w = s_cut[k]*expf(s_alpha[k][tid] - m);
      s_alpha[k][tid] = w; ss += w;
    }
    float inv = 1.0f/(ss + 1e-9f);
    for (int k=0;k<Kk;k++) s_alpha[k][tid] *= inv;
  }
  __syncthreads();

  if (tid < Hh*SHDs){
    int h = tid/SHDs, sg = tid - h*SHDs;
    float a = 0.0f;
    for (int k=0;k<Kk;k++) a += s_alpha[k][h]*s_sh[k][sg];
    s_poolsh[h][sg] = a;
  }
  __syncthreads();

  {
    const int h = tid>>5;
    float a = 0.0f;
    for (int k=0;k<Kk;k++)
      a += s_alpha[k][h]*vproj_all[((size_t)b*Nn + s_srcv[k])*Dd + tid];
    const float* wvsh = Wvg + (size_t)layer*265*Dd + 256*Dd;   // rows 256..264
    #pragma unroll
    for (int sg=0;sg<SHDs;sg++) a += s_poolsh[h][sg]*wvsh[sg*Dd + tid];
    agg_all[(size_t)bn*Dd + tid] = a;
  }
}

// ---------------- upd: node = act(node + agg @ Wo) ----------------
__global__ __launch_bounds__(256) void upd_kernel(
    const float* __restrict__ agg_all, const float* __restrict__ Wog,
    float* __restrict__ node, int layer){
  __shared__ float s_a[32][264];
  const int tid = threadIdx.x;
  const int n0  = blockIdx.x*32;
  const int y   = blockIdx.y;
  { int m = tid>>6; int i4 = (tid&63)*4;
    #pragma unroll
    for (int r=0;r<8;r++){
      int mm = m + r*4;
      *(float4*)&s_a[mm][i4] = *(const float4*)&agg_all[(size_t)(n0+mm)*Dd + i4];
    } }
  __syncthreads();
  const float* W = Wog + (size_t)layer*Dd*Dd;
  const int m0 = (tid>>5)*4;
  const int c0 = y*128 + (tid&31)*4;
  float4 acc[4];
  #pragma unroll
  for (int mm=0;mm<4;mm++) acc[mm] = make_float4(0.f,0.f,0.f,0.f);
  for (int i=0;i<Dd;i+=4){
    float4 a0 = *(const float4*)&s_a[m0+0][i];
    float4 a1 = *(const float4*)&s_a[m0+1][i];
    float4 a2 = *(const float4*)&s_a[m0+2][i];
    float4 a3 = *(const float4*)&s_a[m0+3][i];
    float4 w0 = *(const float4*)&W[(size_t)(i+0)*Dd + c0];
    float4 w1 = *(const float4*)&W[(size_t)(i+1)*Dd + c0];
    float4 w2 = *(const float4*)&W[(size_t)(i+2)*Dd + c0];
    float4 w3 = *(const float4*)&W[(size_t)(i+3)*Dd + c0];
    fma4(acc[0],a0.x,w0); fma4(acc[0],a0.y,w1); fma4(acc[0],a0.z,w2); fma4(acc[0],a0.w,w3);
    fma4(acc[1],a1.x,w0); fma4(acc[1],a1.y,w1); fma4(acc[1],a1.z,w2); fma4(acc[1],a1.w,w3);
    fma4(acc[2],a2.x,w0); fma4(acc[2],a2.y,w1); fma4(acc[2],a2.z,w2); fma4(acc[2],a2.w,w3);
    fma4(acc[3],a3.x,w0); fma4(acc[3],a3.y,w1); fma4(acc[3],a3.z,w2); fma4(acc[3],a3.w,w3);
  }
  #pragma unroll
  for (int mm=0;mm<4;mm++){
    float4 res = *(const float4*)&node[(size_t)(n0+m0+mm)*Dd + c0];
    float4 v = make_float4(res.x+acc[mm].x, res.y+acc[mm].y, res.z+acc[mm].z, res.w+acc[mm].w);
    if (c0 < 64){ v.x=gelu_tanh(v.x); v.y=gelu_tanh(v.y); v.z=gelu_tanh(v.z); v.w=gelu_tanh(v.w); }
    else if (c0 < NSns){ v.x=tanhf(v.x); v.y=tanhf(v.y); v.z=tanhf(v.z); v.w=tanhf(v.w); }
    *(float4*)&node[(size_t)(n0+m0+mm)*Dd + c0] = v;
  }
}

// ---------------- final: out = agg @ Wo_out ----------------
__global__ __launch_bounds__(256) void out_kernel(
    const float* __restrict__ agg_all, const float* __restrict__ Woo, float* __restrict__ out){
  const int tid = threadIdx.x;
  if (tid >= 192) return;
  const int n = blockIdx.x*64 + tid/3;
  const int c = tid - (tid/3)*3;
  float a = 0.0f;
  for (int i=0;i<Dd;i++) a += agg_all[(size_t)n*Dd + i]*Woo[i*3 + c];
  out[(size_t)n*3 + c] = a;
}

extern "C" void kernel_launch(void* const* d_in, const int* in_sizes, int n_in,
                              void* d_out, int out_size, void* d_ws, size_t ws_size,
                              hipStream_t stream){
  const float* x   = (const float*)d_in[0];
  const float* y   = (const float*)d_in[1];
  const float* t   = (const float*)d_in[2];
  const float* We  = (const float*)d_in[3];
  const float* Wk1 = (const float*)d_in[4];
  const float* bk1 = (const float*)d_in[5];
  const float* Wk2 = (const float*)d_in[6];
  const float* Wq  = (const float*)d_in[7];
  const float* Wv  = (const float*)d_in[8];
  const float* Wo  = (const float*)d_in[9];
  const float* Woo = (const float*)d_in[10];
  float* out = (float*)d_out;

  char* ws = (char*)d_ws;
  size_t off = 0;
  int* src = (int*)(ws + off);       off += (size_t)Bb*Nn*Kk*sizeof(int);      // 1 MB
  float* node  = (float*)(ws + off); off += (size_t)Bb*Nn*Dd*sizeof(float);    // 8 MB
  float* qbuf  = (float*)(ws + off); off += (size_t)Bb*Nn*Dd*sizeof(float);    // 8 MB (q, then agg)
  float* hsrc  = (float*)(ws + off); off += (size_t)Bb*Nn*HIDh*sizeof(float);  // 4 MB
  float* hdst  = (float*)(ws + off); off += (size_t)Bb*Nn*HIDh*sizeof(float);  // 4 MB
  float* vproj = (float*)(ws + off); off += (size_t)Bb*Nn*Dd*sizeof(float);    // 8 MB
  float* qw    = (float*)(ws + off); off += (size_t)Bb*Nn*HIDh*Hh*sizeof(float); // 32 MB

  knn_kernel<<<dim3(Bb*Nn), 64, 0, stream>>>(x, src);
  embed_kernel<<<dim3(Bb*Nn), 256, 0, stream>>>(y, t, We, node);

  for (int l=0; l<4; l++){
    proj_kernel<<<dim3(Bb*Nn/32, 6), 256, 0, stream>>>(node, t, Wq, Wk1, bk1, Wv,
                                                       qbuf, hsrc, hdst, vproj, l);
    qw_kernel<<<dim3(Bb*Nn/32, 8), 256, 0, stream>>>(qbuf, Wk2, qw, l);
    attn_kernel<<<dim3(Bb*Nn), 256, 0, stream>>>(x, src, hsrc, hdst, vproj, qw, Wk1, Wv, qbuf, l);
    if (l < 3){
      upd_kernel<<<dim3(Bb*Nn/32, 2), 256, 0, stream>>>(qbuf, Wo, node, l);
    } else {
      out_kernel<<<dim3(Bb*Nn/64), 256, 0, stream>>>(qbuf, Woo, out);
    }
  }
}